// Round 1
// baseline (205.677 us; speedup 1.0000x reference)
//
#include <hip/hip_runtime.h>
#include <hip/hip_bf16.h>

// Problem dims (fixed by setup_inputs)
constexpr int B = 4, H = 8, N = 4096, E = 64, D = 512;   // d_model = H*E = 512
constexpr int BH = B * H;          // 32
constexpr int CHUNK = 64;          // positions per chunk in the scan
constexpr int NCH = N / CHUNK;     // 64 chunks per (b,h)
constexpr float EPS = 1e-5f;

__device__ __forceinline__ float phi(float x) {
    // elu(x) + 1
    return (x > 0.0f) ? (x + 1.0f) : __expf(x);
}

// ---------------------------------------------------------------------------
// Pass 1: per-(bh,chunk) sums of phi(k) and v over the chunk, per dim e.
// grid: BH*NCH blocks, 64 threads (lane = e)
// ---------------------------------------------------------------------------
__global__ void chunk_sums(const float* __restrict__ k, const float* __restrict__ v,
                           float* __restrict__ ksum, float* __restrict__ vsum) {
    int blk = blockIdx.x;            // bh*NCH + ch
    int lane = threadIdx.x;          // e
    int bh = blk / NCH, ch = blk % NCH;
    size_t base = ((size_t)bh * N + (size_t)ch * CHUNK) * E + lane;
    const float* kp = k + base;
    const float* vp = v + base;
    float ks = 0.f, vs = 0.f;
    #pragma unroll 4
    for (int i = 0; i < CHUNK; i++) {
        ks += phi(kp[(size_t)i * E]);
        vs += vp[(size_t)i * E];
    }
    ksum[blk * E + lane] = ks;
    vsum[blk * E + lane] = vs;
}

// ---------------------------------------------------------------------------
// Pass 2: exclusive prefix over chunks (in place). grid: BH blocks, 64 threads
// ---------------------------------------------------------------------------
__global__ void chunk_prefix(float* __restrict__ ksum, float* __restrict__ vsum) {
    int bh = blockIdx.x;
    int lane = threadIdx.x;
    float ka = 0.f, va = 0.f;
    for (int c = 0; c < NCH; c++) {
        int idx = (bh * NCH + c) * E + lane;
        float kk = ksum[idx], vv = vsum[idx];
        ksum[idx] = ka; vsum[idx] = va;
        ka += kk; va += vv;
    }
}

// ---------------------------------------------------------------------------
// Pass 3: sequential scan within each chunk; compute attn, store as bf16 in
// [b, n, h*e] layout.  grid: BH*NCH blocks, 64 threads (lane = e)
// ---------------------------------------------------------------------------
__global__ void scan_attn(const float* __restrict__ q, const float* __restrict__ k,
                          const float* __restrict__ v,
                          const float* __restrict__ ksum, const float* __restrict__ vsum,
                          __hip_bfloat16* __restrict__ attn) {
    int blk = blockIdx.x;
    int lane = threadIdx.x;
    int bh = blk / NCH, ch = blk % NCH;
    int b = bh / H, h = bh % H;
    size_t base = ((size_t)bh * N + (size_t)ch * CHUNK) * E + lane;
    const float* qp = q + base;
    const float* kp = k + base;
    const float* vp = v + base;
    float kc = ksum[blk * E + lane];
    float vc = vsum[blk * E + lane];
    // output row r = b*N + n_global ; col = h*E + lane
    __hip_bfloat16* op = attn + ((size_t)(b * N + ch * CHUNK)) * D + h * E + lane;
    for (int i = 0; i < CHUNK; i++) {
        float kv = kp[(size_t)i * E];
        float qv = qp[(size_t)i * E];
        float vv = vp[(size_t)i * E];
        kc += phi(kv);
        vc += vv;
        float s = phi(qv) * kc;
        // wave-wide sum (64 lanes)
        #pragma unroll
        for (int m = 1; m < 64; m <<= 1) s += __shfl_xor(s, m, 64);
        float scale = s / (s + EPS);
        op[(size_t)i * D] = __float2bfloat16(scale * vc);
    }
}

// ---------------------------------------------------------------------------
// W fp32 -> bf16
// ---------------------------------------------------------------------------
__global__ void convert_w(const float* __restrict__ w, __hip_bfloat16* __restrict__ wb) {
    int i = blockIdx.x * 256 + threadIdx.x;   // grid covers 512*512
    wb[i] = __float2bfloat16(w[i]);
}

// ---------------------------------------------------------------------------
// GEMM: out[M=16384, Nn=512] = attn_bf16 @ W_bf16^T + bias  (fp32 out)
// Both operands row-major with K (=512) contiguous.
// One wave per block, 64x64 tile, mfma_f32_16x16x32_bf16.
// A-frag: lane(m=lane&15, quad=lane>>4) holds A[m][k0+quad*8 .. +8]
// B-frag: lane(n=lane&15, quad)        holds B[n][k0+quad*8 .. +8]
// D: row = quad*4 + r, col = lane&15
// ---------------------------------------------------------------------------
typedef __attribute__((ext_vector_type(8))) short short8;
typedef __attribute__((ext_vector_type(4))) float floatx4;

__global__ void gemm_bf16(const __hip_bfloat16* __restrict__ A,
                          const __hip_bfloat16* __restrict__ Bw,
                          const float* __restrict__ bias,
                          float* __restrict__ out) {
    int tile = blockIdx.x;           // 256 M-tiles x 8 N-tiles
    int tn = tile & 7, tm = tile >> 3;
    int lane = threadIdx.x;
    int lo = lane & 15;
    int quad = lane >> 4;

    floatx4 acc[4][4] = {};
    const short* a_base = (const short*)A + ((size_t)(tm * 64 + lo)) * D + quad * 8;
    const short* b_base = (const short*)Bw + ((size_t)(tn * 64 + lo)) * D + quad * 8;

    for (int k0 = 0; k0 < D; k0 += 32) {
        short8 af[4], bf[4];
        #pragma unroll
        for (int i = 0; i < 4; i++) {
            af[i] = *(const short8*)(a_base + (size_t)i * 16 * D + k0);
            bf[i] = *(const short8*)(b_base + (size_t)i * 16 * D + k0);
        }
        #pragma unroll
        for (int i = 0; i < 4; i++)
            #pragma unroll
            for (int j = 0; j < 4; j++)
                acc[i][j] = __builtin_amdgcn_mfma_f32_16x16x32_bf16(af[i], bf[j], acc[i][j], 0, 0, 0);
    }

    #pragma unroll
    for (int i = 0; i < 4; i++) {
        #pragma unroll
        for (int j = 0; j < 4; j++) {
            int n = tn * 64 + j * 16 + lo;
            float bv = bias[n];
            #pragma unroll
            for (int r = 0; r < 4; r++) {
                int m = tm * 64 + i * 16 + quad * 4 + r;
                out[(size_t)m * D + n] = acc[i][j][r] + bv;
            }
        }
    }
}

// ---------------------------------------------------------------------------

extern "C" void kernel_launch(void* const* d_in, const int* in_sizes, int n_in,
                              void* d_out, int out_size, void* d_ws, size_t ws_size,
                              hipStream_t stream) {
    const float* q   = (const float*)d_in[0];
    const float* k   = (const float*)d_in[1];
    const float* v   = (const float*)d_in[2];
    // d_in[3] = mask (unused)
    const float* W   = (const float*)d_in[4];
    const float* bfc = (const float*)d_in[5];
    float* out = (float*)d_out;

    char* ws = (char*)d_ws;
    __hip_bfloat16* attn = (__hip_bfloat16*)ws;                                   // 16 MiB
    __hip_bfloat16* wb   = (__hip_bfloat16*)(ws + (size_t)16 * 1024 * 1024);      // 512 KiB
    float* ksum = (float*)(ws + (size_t)16 * 1024 * 1024 + 512 * 1024);           // 512 KiB
    float* vsum = ksum + BH * NCH * E;                                            // 512 KiB

    hipLaunchKernelGGL(convert_w, dim3((D * D) / 256), dim3(256), 0, stream, W, wb);
    hipLaunchKernelGGL(chunk_sums, dim3(BH * NCH), dim3(64), 0, stream, k, v, ksum, vsum);
    hipLaunchKernelGGL(chunk_prefix, dim3(BH), dim3(64), 0, stream, ksum, vsum);
    hipLaunchKernelGGL(scan_attn, dim3(BH * NCH), dim3(64), 0, stream, q, k, v, ksum, vsum, attn);
    hipLaunchKernelGGL(gemm_bf16, dim3((B * N / 64) * (D / 64)), dim3(64), 0, stream, attn, wb, bfc, out);
}

// Round 2
// 189.011 us; speedup vs baseline: 1.0882x; 1.0882x over previous
//
#include <hip/hip_runtime.h>
#include <hip/hip_bf16.h>

// Problem dims (fixed by setup_inputs)
constexpr int B = 4, H = 8, N = 4096, E = 64, D = 512;   // d_model = H*E = 512
constexpr int BH = B * H;          // 32
constexpr int CHUNK = 64;          // positions per chunk in the scan
constexpr int NCH = N / CHUNK;     // 64 chunks per (b,h)
constexpr float EPS = 1e-5f;

typedef __attribute__((ext_vector_type(4))) float floatx4;
typedef __attribute__((ext_vector_type(8))) short short8;

__device__ __forceinline__ float phi(float x) {
    // elu(x) + 1
    return (x > 0.0f) ? (x + 1.0f) : __expf(x);
}

// ---------------------------------------------------------------------------
// Pass 1: per-(bh,chunk) sums of phi(k) and v over the chunk, per dim e.
// One wave per chunk, float4 loads. Output TRANSPOSED: ksumT[bh][e][ch].
// grid: 512 blocks x 256 threads (4 waves/block, wave = chunk)
// ---------------------------------------------------------------------------
__global__ void chunk_sums(const float* __restrict__ k, const float* __restrict__ v,
                           float* __restrict__ ksumT, float* __restrict__ vsumT) {
    int wave = (blockIdx.x << 2) | (threadIdx.x >> 6);   // chunk id 0..2047
    int lane = threadIdx.x & 63;
    int bh = wave >> 6, ch = wave & 63;
    int qd = lane >> 4;          // row-phase 0..3
    int c  = lane & 15;          // col-group (4 dims)
    const float* kp = k + ((size_t)bh * N + (size_t)ch * CHUNK) * E;
    const float* vp = v + ((size_t)bh * N + (size_t)ch * CHUNK) * E;
    floatx4 ks = {0.f, 0.f, 0.f, 0.f}, vs = {0.f, 0.f, 0.f, 0.f};
    #pragma unroll
    for (int i = 0; i < 16; i++) {
        int off = (i * 4 + qd) * E + c * 4;
        floatx4 kv = *(const floatx4*)(kp + off);
        floatx4 vv = *(const floatx4*)(vp + off);
        #pragma unroll
        for (int j = 0; j < 4; j++) ks[j] += phi(kv[j]);
        vs += vv;
    }
    // reduce across the 4 row-phases (lanes differing in bits 4,5)
    #pragma unroll
    for (int j = 0; j < 4; j++) {
        ks[j] += __shfl_xor(ks[j], 16, 64);
        ks[j] += __shfl_xor(ks[j], 32, 64);
        vs[j] += __shfl_xor(vs[j], 16, 64);
        vs[j] += __shfl_xor(vs[j], 32, 64);
    }
    // lane l owns dim d = 4*(l&15) + (l>>4): write component qd
    int d = c * 4 + qd;
    ksumT[(size_t)(bh * E + d) * NCH + ch] = ks[qd];
    vsumT[(size_t)(bh * E + d) * NCH + ch] = vs[qd];
}

// ---------------------------------------------------------------------------
// Pass 2: exclusive prefix over chunks, in place, one wave per (bh,e).
// lane = chunk; contiguous loads on the transposed layout.
// grid: 512 blocks x 256 threads (2048 waves)
// ---------------------------------------------------------------------------
__global__ void chunk_prefix(float* __restrict__ ksumT, float* __restrict__ vsumT) {
    int wid = (blockIdx.x << 2) | (threadIdx.x >> 6);   // bh*E + e, 0..2047
    int lane = threadIdx.x & 63;                        // chunk
    size_t idx = (size_t)wid * NCH + lane;
    float x = ksumT[idx], y = vsumT[idx];
    float ox = x, oy = y;
    #pragma unroll
    for (int dlt = 1; dlt < 64; dlt <<= 1) {
        float tx = __shfl_up(x, dlt, 64);
        float ty = __shfl_up(y, dlt, 64);
        if (lane >= dlt) { x += tx; y += ty; }
    }
    ksumT[idx] = x - ox;   // exclusive
    vsumT[idx] = y - oy;
}

// ---------------------------------------------------------------------------
// Pass 3: sequential scan within each chunk; compute attn, store bf16 in
// [b, n, h*e] layout. One wave per chunk, lane = e, 4-position prefetch.
// grid: 512 blocks x 256 threads
// ---------------------------------------------------------------------------
__global__ void scan_attn(const float* __restrict__ q, const float* __restrict__ k,
                          const float* __restrict__ v,
                          const float* __restrict__ ksumT, const float* __restrict__ vsumT,
                          __hip_bfloat16* __restrict__ attn) {
    int wave = (blockIdx.x << 2) | (threadIdx.x >> 6);   // chunk id
    int lane = threadIdx.x & 63;                         // e
    int bh = wave >> 6, ch = wave & 63;
    int b = bh >> 3, h = bh & 7;
    size_t base = ((size_t)bh * N + (size_t)ch * CHUNK) * E + lane;
    const float* qp = q + base;
    const float* kp = k + base;
    const float* vp = v + base;
    float kc = ksumT[(size_t)(bh * E + lane) * NCH + ch];
    float vc = vsumT[(size_t)(bh * E + lane) * NCH + ch];
    __hip_bfloat16* op = attn + ((size_t)(b * N + ch * CHUNK)) * D + h * E + lane;

    float ka[4], qa[4], va[4];
    #pragma unroll
    for (int j = 0; j < 4; j++) {
        ka[j] = kp[(size_t)j * E];
        qa[j] = qp[(size_t)j * E];
        va[j] = vp[(size_t)j * E];
    }
    for (int g = 0; g < 16; g++) {
        float kb[4], qb[4], vb[4];
        if (g < 15) {
            const float* kp2 = kp + (size_t)(g + 1) * 4 * E;
            const float* qp2 = qp + (size_t)(g + 1) * 4 * E;
            const float* vp2 = vp + (size_t)(g + 1) * 4 * E;
            #pragma unroll
            for (int j = 0; j < 4; j++) {
                kb[j] = kp2[(size_t)j * E];
                qb[j] = qp2[(size_t)j * E];
                vb[j] = vp2[(size_t)j * E];
            }
        }
        #pragma unroll
        for (int j = 0; j < 4; j++) {
            kc += phi(ka[j]);
            vc += va[j];
            float s = phi(qa[j]) * kc;
            #pragma unroll
            for (int m = 1; m < 64; m <<= 1) s += __shfl_xor(s, m, 64);
            float scale = s / (s + EPS);
            op[(size_t)(g * 4 + j) * D] = __float2bfloat16(scale * vc);
        }
        #pragma unroll
        for (int j = 0; j < 4; j++) { ka[j] = kb[j]; qa[j] = qb[j]; va[j] = vb[j]; }
    }
}

// ---------------------------------------------------------------------------
// W fp32 -> bf16
// ---------------------------------------------------------------------------
__global__ void convert_w(const float* __restrict__ w, __hip_bfloat16* __restrict__ wb) {
    int i = blockIdx.x * 256 + threadIdx.x;   // grid covers 512*512
    wb[i] = __float2bfloat16(w[i]);
}

// ---------------------------------------------------------------------------
// GEMM: out[M=16384, Nn=512] = attn_bf16 @ W_bf16^T + bias  (fp32 out)
// One wave per block, 64x64 tile, mfma_f32_16x16x32_bf16.
// XCD swizzle: tm = tile & 255, tn = tile >> 8 → the 8 blocks sharing an
// A-tile are 256 apart in blockIdx (256%8==0) → same XCD → A served by one L2.
// ---------------------------------------------------------------------------
__global__ void gemm_bf16(const __hip_bfloat16* __restrict__ A,
                          const __hip_bfloat16* __restrict__ Bw,
                          const float* __restrict__ bias,
                          float* __restrict__ out) {
    int tile = blockIdx.x;           // 2048 = 256 M-tiles x 8 N-tiles
    int tm = tile & 255, tn = tile >> 8;
    int lane = threadIdx.x;
    int lo = lane & 15;
    int quad = lane >> 4;

    floatx4 acc[4][4] = {};
    const short* a_base = (const short*)A + ((size_t)(tm * 64 + lo)) * D + quad * 8;
    const short* b_base = (const short*)Bw + ((size_t)(tn * 64 + lo)) * D + quad * 8;

    for (int k0 = 0; k0 < D; k0 += 32) {
        short8 af[4], bf[4];
        #pragma unroll
        for (int i = 0; i < 4; i++) {
            af[i] = *(const short8*)(a_base + (size_t)i * 16 * D + k0);
            bf[i] = *(const short8*)(b_base + (size_t)i * 16 * D + k0);
        }
        #pragma unroll
        for (int i = 0; i < 4; i++)
            #pragma unroll
            for (int j = 0; j < 4; j++)
                acc[i][j] = __builtin_amdgcn_mfma_f32_16x16x32_bf16(af[i], bf[j], acc[i][j], 0, 0, 0);
    }

    #pragma unroll
    for (int i = 0; i < 4; i++) {
        #pragma unroll
        for (int j = 0; j < 4; j++) {
            int n = tn * 64 + j * 16 + lo;
            float bv = bias[n];
            #pragma unroll
            for (int r = 0; r < 4; r++) {
                int m = tm * 64 + i * 16 + quad * 4 + r;
                out[(size_t)m * D + n] = acc[i][j][r] + bv;
            }
        }
    }
}

// ---------------------------------------------------------------------------

extern "C" void kernel_launch(void* const* d_in, const int* in_sizes, int n_in,
                              void* d_out, int out_size, void* d_ws, size_t ws_size,
                              hipStream_t stream) {
    const float* q   = (const float*)d_in[0];
    const float* k   = (const float*)d_in[1];
    const float* v   = (const float*)d_in[2];
    // d_in[3] = mask (unused)
    const float* W   = (const float*)d_in[4];
    const float* bfc = (const float*)d_in[5];
    float* out = (float*)d_out;

    char* ws = (char*)d_ws;
    __hip_bfloat16* attn = (__hip_bfloat16*)ws;                                   // 16 MiB
    __hip_bfloat16* wb   = (__hip_bfloat16*)(ws + (size_t)16 * 1024 * 1024);      // 512 KiB
    float* ksumT = (float*)(ws + (size_t)16 * 1024 * 1024 + 512 * 1024);          // 512 KiB
    float* vsumT = ksumT + BH * NCH * E;                                          // 512 KiB

    hipLaunchKernelGGL(convert_w, dim3((D * D) / 256), dim3(256), 0, stream, W, wb);
    hipLaunchKernelGGL(chunk_sums, dim3(BH * NCH / 4), dim3(256), 0, stream, k, v, ksumT, vsumT);
    hipLaunchKernelGGL(chunk_prefix, dim3(BH * E / 4), dim3(256), 0, stream, ksumT, vsumT);
    hipLaunchKernelGGL(scan_attn, dim3(BH * NCH / 4), dim3(256), 0, stream, q, k, v, ksumT, vsumT, attn);
    hipLaunchKernelGGL(gemm_bf16, dim3((B * N / 64) * (D / 64)), dim3(64), 0, stream, attn, wb, bfc, out);
}

// Round 3
// 166.763 us; speedup vs baseline: 1.2333x; 1.1334x over previous
//
#include <hip/hip_runtime.h>
#include <hip/hip_bf16.h>

// Problem dims (fixed by setup_inputs)
constexpr int B = 4, H = 8, N = 4096, E = 64, D = 512;   // d_model = H*E = 512
constexpr int BH = B * H;          // 32
constexpr int CHUNK = 32;          // positions per chunk in the scan
constexpr int NCH = N / CHUNK;     // 128 chunks per (b,h)
constexpr float EPS = 1e-5f;

typedef __attribute__((ext_vector_type(4))) float floatx4;
typedef __attribute__((ext_vector_type(8))) short short8;

__device__ __forceinline__ float phi(float x) {
    // elu(x) + 1
    return (x > 0.0f) ? (x + 1.0f) : __expf(x);
}

// ---------------------------------------------------------------------------
// Pass 1: per-(bh,chunk) sums of phi(k) and v over the chunk, per dim e.
// One wave per chunk, float4 loads. Output TRANSPOSED: ksumT[bh][e][ch].
// grid: 1024 blocks x 256 threads (4 waves/block, wave = chunk, 4096 waves)
// ---------------------------------------------------------------------------
__global__ void chunk_sums(const float* __restrict__ k, const float* __restrict__ v,
                           float* __restrict__ ksumT, float* __restrict__ vsumT) {
    int wave = (blockIdx.x << 2) | (threadIdx.x >> 6);   // chunk id 0..4095
    int lane = threadIdx.x & 63;
    int bh = wave >> 7, ch = wave & 127;
    int qd = lane >> 4;          // row-phase 0..3
    int c  = lane & 15;          // col-group (4 dims)
    const float* kp = k + ((size_t)bh * N + (size_t)ch * CHUNK) * E;
    const float* vp = v + ((size_t)bh * N + (size_t)ch * CHUNK) * E;
    floatx4 ks = {0.f, 0.f, 0.f, 0.f}, vs = {0.f, 0.f, 0.f, 0.f};
    #pragma unroll
    for (int i = 0; i < CHUNK / 4; i++) {
        int off = (i * 4 + qd) * E + c * 4;
        floatx4 kv = *(const floatx4*)(kp + off);
        floatx4 vv = *(const floatx4*)(vp + off);
        #pragma unroll
        for (int j = 0; j < 4; j++) ks[j] += phi(kv[j]);
        vs += vv;
    }
    // reduce across the 4 row-phases (lanes differing in bits 4,5)
    #pragma unroll
    for (int j = 0; j < 4; j++) {
        ks[j] += __shfl_xor(ks[j], 16, 64);
        ks[j] += __shfl_xor(ks[j], 32, 64);
        vs[j] += __shfl_xor(vs[j], 16, 64);
        vs[j] += __shfl_xor(vs[j], 32, 64);
    }
    // lane l owns dim d = 4*(l&15) + (l>>4): write component qd
    int d = c * 4 + qd;
    ksumT[(size_t)(bh * E + d) * NCH + ch] = ks[qd];
    vsumT[(size_t)(bh * E + d) * NCH + ch] = vs[qd];
}

// ---------------------------------------------------------------------------
// Pass 2: exclusive prefix over 128 chunks, in place, one wave per (bh,e).
// lane handles chunks {lane, 64+lane}; contiguous loads on transposed layout.
// grid: 512 blocks x 256 threads (2048 waves)
// ---------------------------------------------------------------------------
__global__ void chunk_prefix(float* __restrict__ ksumT, float* __restrict__ vsumT) {
    int wid = (blockIdx.x << 2) | (threadIdx.x >> 6);   // bh*E + e, 0..2047
    int lane = threadIdx.x & 63;
    size_t base = (size_t)wid * NCH;
    float x0 = ksumT[base + lane],      y0 = vsumT[base + lane];
    float x1 = ksumT[base + 64 + lane], y1 = vsumT[base + 64 + lane];
    float ox0 = x0, oy0 = y0, ox1 = x1, oy1 = y1;
    #pragma unroll
    for (int dlt = 1; dlt < 64; dlt <<= 1) {
        float t0 = __shfl_up(x0, dlt, 64);
        float u0 = __shfl_up(y0, dlt, 64);
        float t1 = __shfl_up(x1, dlt, 64);
        float u1 = __shfl_up(y1, dlt, 64);
        if (lane >= dlt) { x0 += t0; y0 += u0; x1 += t1; y1 += u1; }
    }
    float tx = __shfl(x0, 63, 64);   // total of first half
    float ty = __shfl(y0, 63, 64);
    x1 += tx; y1 += ty;
    ksumT[base + lane]      = x0 - ox0;   // exclusive
    vsumT[base + lane]      = y0 - oy0;
    ksumT[base + 64 + lane] = x1 - ox1;
    vsumT[base + 64 + lane] = y1 - oy1;
}

// ---------------------------------------------------------------------------
// Pass 3: sequential scan within each 32-chunk; batched ILP reductions.
// One wave per chunk, lane = e. Store bf16 attn in [b, n, h*e] layout.
// grid: 1024 blocks x 256 threads (4096 waves)
// ---------------------------------------------------------------------------
__global__ void scan_attn(const float* __restrict__ q, const float* __restrict__ k,
                          const float* __restrict__ v,
                          const float* __restrict__ ksumT, const float* __restrict__ vsumT,
                          __hip_bfloat16* __restrict__ attn) {
    int wave = (blockIdx.x << 2) | (threadIdx.x >> 6);   // chunk id 0..4095
    int lane = threadIdx.x & 63;                         // e
    int bh = wave >> 7, ch = wave & 127;
    int b = bh >> 3, h = bh & 7;
    size_t base = ((size_t)bh * N + (size_t)ch * CHUNK) * E + lane;
    const float* qp = q + base;
    const float* kp = k + base;
    const float* vp = v + base;
    float kc = ksumT[(size_t)(bh * E + lane) * NCH + ch];
    float vc = vsumT[(size_t)(bh * E + lane) * NCH + ch];
    __hip_bfloat16* op = attn + ((size_t)(b * N + ch * CHUNK)) * D + h * E + lane;

    #pragma unroll
    for (int g = 0; g < 2; g++) {
        float kA[16], qA[16], vA[16], pr[16], vs[16];
        // 48 independent coalesced loads (256B each) — issue all, then compute
        #pragma unroll
        for (int j = 0; j < 16; j++) {
            size_t o = (size_t)(g * 16 + j) * E;
            kA[j] = kp[o]; qA[j] = qp[o]; vA[j] = vp[o];
        }
        // lane-local serial scan (cheap: 1 fma-chain per position)
        #pragma unroll
        for (int j = 0; j < 16; j++) {
            kc += phi(kA[j]);
            vc += vA[j];
            pr[j] = phi(qA[j]) * kc;
            vs[j] = vc;
        }
        // 16 INDEPENDENT wave-wide butterflies (ILP hides swizzle latency)
        #pragma unroll
        for (int m = 1; m < 64; m <<= 1) {
            #pragma unroll
            for (int j = 0; j < 16; j++) pr[j] += __shfl_xor(pr[j], m, 64);
        }
        #pragma unroll
        for (int j = 0; j < 16; j++) {
            float s = pr[j];
            op[(size_t)(g * 16 + j) * D] = __float2bfloat16(s / (s + EPS) * vs[j]);
        }
    }
}

// ---------------------------------------------------------------------------
// W fp32 -> bf16
// ---------------------------------------------------------------------------
__global__ void convert_w(const float* __restrict__ w, __hip_bfloat16* __restrict__ wb) {
    int i = blockIdx.x * 256 + threadIdx.x;   // grid covers 512*512
    wb[i] = __float2bfloat16(w[i]);
}

// ---------------------------------------------------------------------------
// GEMM: out[M=16384, 512] = attn_bf16 @ W_bf16^T + bias  (fp32 out)
// m97-style: 128x128 block tile, 256 threads (4 waves, 2x2 wave grid),
// BK=64, global_load_lds width-16 staging, XOR-swizzled LDS columns.
// LDS col-group swizzle: global colgrp g of row r stored at grp g^(r&7).
//   - staging instr covers 8 rows x 8 colgrps = 64 lanes x 16B (contiguous LDS)
//   - frag ds_read_b128 at ((kk*4+quad)^(lo&7)) -> uniform bank distribution
// grid: 128 M-tiles x 4 N-tiles = 512 blocks.
// ---------------------------------------------------------------------------
constexpr int TM = 128, TN = 128, BK = 64;

__global__ __launch_bounds__(256, 2) void gemm_bf16(
        const __hip_bfloat16* __restrict__ A,
        const __hip_bfloat16* __restrict__ Bw,
        const float* __restrict__ bias,
        float* __restrict__ out) {
    __shared__ short Alds[TM * BK];
    __shared__ short Blds[TN * BK];
    int tile = blockIdx.x;           // 512 = 128 mtiles x 4 ntiles
    int tm = tile >> 2, tn = tile & 3;
    int tid = threadIdx.x;
    int w = tid >> 6;                // wave 0..3
    int lane = tid & 63;
    int lo = lane & 15, quad = lane >> 4;
    int wm = w & 1, wn = w >> 1;

    int srow = lane >> 3;            // 0..7 (row within 8-row staging group)
    int cg = lane & 7;               // colgrp slot this lane fills

    floatx4 acc[4][4] = {};

    const short* Ag = (const short*)A;
    const short* Bg = (const short*)Bw;

    for (int k0 = 0; k0 < D; k0 += BK) {
        __syncthreads();
        #pragma unroll
        for (int t = 0; t < 4; t++) {
            int r = w * 32 + t * 8 + srow;
            int gg = cg ^ srow;                       // global colgrp to fetch
            const short* ga = Ag + (size_t)(tm * TM + r) * D + k0 + gg * 8;
            const short* gb = Bg + (size_t)(tn * TN + r) * D + k0 + gg * 8;
            __builtin_amdgcn_global_load_lds(
                (const __attribute__((address_space(1))) void*)ga,
                (__attribute__((address_space(3))) void*)&Alds[(w * 32 + t * 8) * BK],
                16, 0, 0);
            __builtin_amdgcn_global_load_lds(
                (const __attribute__((address_space(1))) void*)gb,
                (__attribute__((address_space(3))) void*)&Blds[(w * 32 + t * 8) * BK],
                16, 0, 0);
        }
        __syncthreads();
        #pragma unroll
        for (int kk = 0; kk < 2; kk++) {
            short8 af[4], bf[4];
            #pragma unroll
            for (int i = 0; i < 4; i++) {
                int ra = wm * 64 + i * 16 + lo;
                af[i] = *(const short8*)&Alds[ra * BK + (((kk << 2) | quad) ^ (lo & 7)) * 8];
                int rb = wn * 64 + i * 16 + lo;
                bf[i] = *(const short8*)&Blds[rb * BK + (((kk << 2) | quad) ^ (lo & 7)) * 8];
            }
            #pragma unroll
            for (int i = 0; i < 4; i++)
                #pragma unroll
                for (int j = 0; j < 4; j++)
                    acc[i][j] = __builtin_amdgcn_mfma_f32_16x16x32_bf16(af[i], bf[j], acc[i][j], 0, 0, 0);
        }
    }

    #pragma unroll
    for (int i = 0; i < 4; i++) {
        #pragma unroll
        for (int j = 0; j < 4; j++) {
            int n = tn * TN + wn * 64 + j * 16 + lo;
            float bv = bias[n];
            #pragma unroll
            for (int r = 0; r < 4; r++) {
                int m = tm * TM + wm * 64 + i * 16 + quad * 4 + r;
                out[(size_t)m * D + n] = acc[i][j][r] + bv;
            }
        }
    }
}

// ---------------------------------------------------------------------------

extern "C" void kernel_launch(void* const* d_in, const int* in_sizes, int n_in,
                              void* d_out, int out_size, void* d_ws, size_t ws_size,
                              hipStream_t stream) {
    const float* q   = (const float*)d_in[0];
    const float* k   = (const float*)d_in[1];
    const float* v   = (const float*)d_in[2];
    // d_in[3] = mask (unused)
    const float* W   = (const float*)d_in[4];
    const float* bfc = (const float*)d_in[5];
    float* out = (float*)d_out;

    char* ws = (char*)d_ws;
    __hip_bfloat16* attn = (__hip_bfloat16*)ws;                                   // 16 MiB
    __hip_bfloat16* wb   = (__hip_bfloat16*)(ws + (size_t)16 * 1024 * 1024);      // 512 KiB
    float* ksumT = (float*)(ws + (size_t)16 * 1024 * 1024 + 512 * 1024);          // 1 MiB
    float* vsumT = ksumT + BH * NCH * E;                                          // 1 MiB

    hipLaunchKernelGGL(convert_w, dim3((D * D) / 256), dim3(256), 0, stream, W, wb);
    hipLaunchKernelGGL(chunk_sums, dim3(BH * NCH / 4), dim3(256), 0, stream, k, v, ksumT, vsumT);
    hipLaunchKernelGGL(chunk_prefix, dim3(BH * E / 4), dim3(256), 0, stream, ksumT, vsumT);
    hipLaunchKernelGGL(scan_attn, dim3(BH * NCH / 4), dim3(256), 0, stream, q, k, v, ksumT, vsumT, attn);
    hipLaunchKernelGGL(gemm_bf16, dim3((B * N / TM) * (D / TN)), dim3(256), 0, stream, attn, wb, bfc, out);
}